// Round 7
// baseline (240.830 us; speedup 1.0000x reference)
//
#include <hip/hip_runtime.h>
#include <math.h>

typedef _Float16 f16x8 __attribute__((ext_vector_type(8)));
typedef float    f32x4 __attribute__((ext_vector_type(4)));

constexpr int B_ = 256, S_ = 512, D_ = 256, A_ = 128;

__device__ __forceinline__ float tanh_fast(float v) {
    // tanh(v) = 1 - 2/(1 + e^{2v}); correct at +-inf. ~2e-6 abs err.
    return 1.0f - 2.0f / (1.0f + __expf(2.0f * v));
}

// ---- K0: pack W into MFMA B-fragment order, f16 hi + lo (verified round 3) --
// B-frag (nf, ks): lane l supplies B[k=32ks+8(l>>4)+i][n=16nf+(l&15)], i=0..7.
// Packed at (((ks*8 + nf)*64 + l)*8 + i).
__global__ __launch_bounds__(256) void k_packW(const float* __restrict__ W,
                                               _Float16* __restrict__ Wh,
                                               _Float16* __restrict__ Wl)
{
    int tid = blockIdx.x * 256 + threadIdx.x;   // 0..4095
    int l  = tid & 63;
    int nf = (tid >> 6) & 7;
    int ks = tid >> 9;
    int n  = nf * 16 + (l & 15);
    int k0 = ks * 32 + ((l >> 4) & 3) * 8;
    f16x8 hi, lo;
#pragma unroll
    for (int i = 0; i < 8; ++i) {
        float v = W[(k0 + i) * A_ + n];
        _Float16 h = (_Float16)v;
        hi[i] = h;
        lo[i] = (_Float16)(v - (float)h);
    }
    *(f16x8*)(Wh + (size_t)tid * 8) = hi;
    *(f16x8*)(Wl + (size_t)tid * 8) = lo;
}

// ---- Fused per-b kernel: 256 blocks x 512 thr (8 waves) ---------------------
// Phase 1: 16 tiles x 32 rows. Wave (mth = wv>>2, nfp = wv&3) computes rows
// [16mth,+16) x att cols [32nfp,+32): reads HALF the tile, reuses A-frags for
// 2 nf (LDS reads halved vs 1-nf/wave). x staged f32 in LDS, double-buffered,
// ONE barrier per tile; hi/lo split at read time. B-frags register-resident.
__global__ __launch_bounds__(512, 2) void k_fused(
    const float* __restrict__ x, const _Float16* __restrict__ Wh,
    const _Float16* __restrict__ Wl, const float* __restrict__ bvec,
    const float* __restrict__ u, float* __restrict__ out)
{
    __shared__ float xbuf[2][16][2][64][4];  // [par][frag][half][lane][4 f32] = 64 KB
    __shared__ float sc[S_];                 // 2 KB scores
    __shared__ float part[2][4][32];         // 1 KB row partials (per nfp)
    __shared__ float red[8];
    float* pbuf = &xbuf[0][0][0][0][0];      // phase-3 alias: [8][256] = 8 KB

    const int t    = threadIdx.x;
    const int lane = t & 63, wv = t >> 6;
    const int lr   = lane & 15, lg = lane >> 4;
    const int mth  = wv >> 2;                // row half 0/1
    const int nfp  = wv & 3;                 // nf pair 0..3
    const int b    = blockIdx.x;
    const float* __restrict__ xb = x + (size_t)b * S_ * D_;

    // --- B fragments (pre-packed): nf = 2nfp, 2nfp+1; hi+lo; 8 ks = 128 VGPR
    f16x8 Bh[8][2], Bl[8][2];
#pragma unroll
    for (int ks = 0; ks < 8; ++ks)
#pragma unroll
        for (int j = 0; j < 2; ++j) {
            int nf = 2 * nfp + j;
            Bh[ks][j] = *(const f16x8*)(Wh + ((size_t)(ks * 8 + nf) * 64 + lane) * 8);
            Bl[ks][j] = *(const f16x8*)(Wl + ((size_t)(ks * 8 + nf) * 64 + lane) * 8);
        }
    const float bb0 = bvec[(2 * nfp + 0) * 16 + lr], uu0 = u[(2 * nfp + 0) * 16 + lr];
    const float bb1 = bvec[(2 * nfp + 1) * 16 + lr], uu1 = u[(2 * nfp + 1) * 16 + lr];

    // staging: thread stages frags f = {2wv, 2wv+1} of each tile (f = mt*8+ks)
    float4 ld[2][2];

#define K1_ISSUE(TT)                                                              \
    {                                                                             \
        _Pragma("unroll")                                                         \
        for (int ff = 0; ff < 2; ++ff) {                                          \
            int f = wv * 2 + ff;                                                  \
            const float* p = xb + (size_t)((TT) * 32 + ((f >> 3) << 4) + lr) * D_ \
                                + ((f & 7) << 5) + (lg << 3);                     \
            ld[ff][0] = *(const float4*)p;                                        \
            ld[ff][1] = *(const float4*)(p + 4);                                  \
        }                                                                         \
    }
#define K1_STAGE(P)                                                               \
    {                                                                             \
        _Pragma("unroll")                                                         \
        for (int ff = 0; ff < 2; ++ff) {                                          \
            int f = wv * 2 + ff;                                                  \
            *(float4*)&xbuf[P][f][0][lane][0] = ld[ff][0];                        \
            *(float4*)&xbuf[P][f][1][lane][0] = ld[ff][1];                        \
        }                                                                         \
    }

    // ---- Phase 1 ----
    K1_ISSUE(0)
    K1_STAGE(0)

    for (int tt = 0; tt < 16; ++tt) {
        __syncthreads();                     // buf[tt&1] staged; prior reads done
        if (tt > 0 && t < 32) {              // finalize scores of tile tt-1
            const float* pp = &part[(tt - 1) & 1][0][t];
            sc[(tt - 1) * 32 + t] = __expf(pp[0] + pp[32] + pp[64] + pp[96]);
        }
        if (tt < 15) K1_ISSUE(tt + 1)        // issue next tile's global loads

        const int p = tt & 1;
        f32x4 acc0 = {0.f, 0.f, 0.f, 0.f}, acc1 = {0.f, 0.f, 0.f, 0.f};
#pragma unroll
        for (int ks = 0; ks < 8; ++ks) {
            const int f = mth * 8 + ks;
            f32x4 a0 = *(const f32x4*)&xbuf[p][f][0][lane][0];
            f32x4 a1 = *(const f32x4*)&xbuf[p][f][1][lane][0];
            f16x8 ah, al;
#pragma unroll
            for (int i = 0; i < 4; ++i) {
                _Float16 h0 = (_Float16)a0[i];
                _Float16 h1 = (_Float16)a1[i];
                ah[i]     = h0; al[i]     = (_Float16)(a0[i] - (float)h0);
                ah[4 + i] = h1; al[4 + i] = (_Float16)(a1[i] - (float)h1);
            }
            acc0 = __builtin_amdgcn_mfma_f32_16x16x32_f16(ah, Bh[ks][0], acc0, 0, 0, 0);
            acc0 = __builtin_amdgcn_mfma_f32_16x16x32_f16(ah, Bl[ks][0], acc0, 0, 0, 0);
            acc0 = __builtin_amdgcn_mfma_f32_16x16x32_f16(al, Bh[ks][0], acc0, 0, 0, 0);
            acc1 = __builtin_amdgcn_mfma_f32_16x16x32_f16(ah, Bh[ks][1], acc1, 0, 0, 0);
            acc1 = __builtin_amdgcn_mfma_f32_16x16x32_f16(ah, Bl[ks][1], acc1, 0, 0, 0);
            acc1 = __builtin_amdgcn_mfma_f32_16x16x32_f16(al, Bh[ks][1], acc1, 0, 0, 0);
        }
        // epilogue: rows 16mth + lg*4 + r; cols = wave's 32 (2 nf x 16 lr)
#pragma unroll
        for (int r = 0; r < 4; ++r) {
            float s = tanh_fast(acc0[r] + bb0) * uu0 + tanh_fast(acc1[r] + bb1) * uu1;
            s += __shfl_xor(s, 8, 64);
            s += __shfl_xor(s, 4, 64);
            s += __shfl_xor(s, 2, 64);
            s += __shfl_xor(s, 1, 64);
            if (lr == 0) part[tt & 1][nfp][mth * 16 + lg * 4 + r] = s;
        }
        if (tt < 15) K1_STAGE((tt + 1) & 1)  // write other buffer: no barrier needed
    }
    __syncthreads();                         // part (tile 15, parity 1) visible
    if (t < 32) {
        const float* pp = &part[1][0][t];
        sc[15 * 32 + t] = __expf(pp[0] + pp[32] + pp[64] + pp[96]);
    }
    __syncthreads();                         // sc complete; xbuf reads all done
#undef K1_ISSUE
#undef K1_STAGE

    // ---- Phase 2: denominator ----
    {
        float v = sc[wv * 64 + lane];
#pragma unroll
        for (int m = 32; m >= 1; m >>= 1) v += __shfl_xor(v, m, 64);
        if (lane == 0) red[wv] = v;
    }
    __syncthreads();
    float denom = 0.f;
#pragma unroll
    for (int i = 0; i < 8; ++i) denom += red[i];
    const float inv = 1.0f / (denom + 1e-8f);

    // ---- Phase 3: out[b,d] = sum_s x[b,s,d]*sc[s] * inv (x L1/L2-hot) ----
    const float* xp = xb + (size_t)(wv * 64) * D_ + lane * 4;
    f32x4 a0 = {0.f, 0.f, 0.f, 0.f}, a1 = {0.f, 0.f, 0.f, 0.f};
#pragma unroll 8
    for (int j = 0; j < 64; j += 2) {
        float4 va = *(const float4*)(xp + (size_t)j * D_);
        float4 vb = *(const float4*)(xp + (size_t)(j + 1) * D_);
        float s0 = sc[wv * 64 + j], s1 = sc[wv * 64 + j + 1];
        a0[0] = fmaf(va.x, s0, a0[0]); a0[1] = fmaf(va.y, s0, a0[1]);
        a0[2] = fmaf(va.z, s0, a0[2]); a0[3] = fmaf(va.w, s0, a0[3]);
        a1[0] = fmaf(vb.x, s1, a1[0]); a1[1] = fmaf(vb.y, s1, a1[1]);
        a1[2] = fmaf(vb.z, s1, a1[2]); a1[3] = fmaf(vb.w, s1, a1[3]);
    }
    a0[0] += a1[0]; a0[1] += a1[1]; a0[2] += a1[2]; a0[3] += a1[3];
    *(f32x4*)&pbuf[wv * 256 + lane * 4] = a0;
    __syncthreads();

    if (t < D_) {
        float r = 0.f;
#pragma unroll
        for (int i = 0; i < 8; ++i) r += pbuf[i * 256 + t];
        out[b * D_ + t] = r * inv;
    }
}

extern "C" void kernel_launch(void* const* d_in, const int* in_sizes, int n_in,
                              void* d_out, int out_size, void* d_ws, size_t ws_size,
                              hipStream_t stream)
{
    const float* x    = (const float*)d_in[0];
    const float* W    = (const float*)d_in[1];
    const float* bvec = (const float*)d_in[2];
    const float* u    = (const float*)d_in[3];
    float* out = (float*)d_out;

    _Float16* Wh = (_Float16*)d_ws;                     // 64 KB
    _Float16* Wl = (_Float16*)((char*)d_ws + 65536);    // 64 KB

    k_packW<<<16, 256, 0, stream>>>(W, Wh, Wl);
    k_fused<<<B_, 512, 0, stream>>>(x, Wh, Wl, bvec, u, out);
}